// Round 6
// baseline (133.939 us; speedup 1.0000x reference)
//
#include <hip/hip_runtime.h>

#define IN_DIM  4096
#define OUT_DIM 11008
#define NSUB    1376
#define KSQ     256
#define DSUB    8
#define BATCH   32

#define DTILE   8                    // subspaces per block
#define NTILE   64                   // output cols per block
#define KC      64                   // k per chunk
#define KSPLIT  16                   // k-blocks per output column
#define KPB     (IN_DIM / KSPLIT)    // 256
#define NCHUNK  (KPB / KC)           // 4
#define NBLK    (OUT_DIM / NTILE)    // 172
#define NBLKP   176                  // padded: 8 XCDs * 22
#define NPX     (NBLKP / 8)          // 22 nblk per XCD
#define GRID_MAIN (NBLKP * KSPLIT)   // 2816

typedef unsigned short ushort_t;
typedef unsigned int   uint_t;
typedef unsigned char  uchar_t;
typedef __attribute__((ext_vector_type(8))) short bf16x8;
typedef __attribute__((ext_vector_type(4))) float f32x4;

// workspace layout (bytes) — no bf16 pack buffers anymore
#define IDXT_OFF 0                                // idx8T [NSUB][IN_DIM] u8 (5.6 MB)
#define SLAB_OFF (NSUB * IN_DIM)                  // f32 slabs [KSPLIT][BATCH][OUT_DIM] (22.5 MB)
#define IDXT_BLK ((IN_DIM / 128) * (NSUB / 32))   // 1376

__device__ __forceinline__ ushort_t f2bf(float f) {
    union { float f; uint_t u; } a; a.f = f;
    uint_t u = a.u;
    u += 0x7fffu + ((u >> 16) & 1u);   // round-to-nearest-even
    return (ushort_t)(u >> 16);
}
__device__ __forceinline__ uint_t pack2(float lo, float hi) {
    return (uint_t)f2bf(lo) | ((uint_t)f2bf(hi) << 16);
}

// ---- prep: transpose idx [k][d] int32 -> idx8T [d][k] uint8 (only job) ----
__global__ __launch_bounds__(256) void pq_prep(
    const int* __restrict__ idx, uchar_t* __restrict__ idx8T)
{
    __shared__ uchar_t sT[32][144];
    const int t = threadIdx.x;
    const int k0 = (blockIdx.x & 31) * 128, d0 = (blockIdx.x >> 5) * 32;
    #pragma unroll
    for (int p = 0; p < 16; ++p) {
        int f = p * 256 + t;           // 0..4095
        int kk = f >> 5, dd = f & 31;
        sT[dd][kk] = (uchar_t)idx[(size_t)(k0 + kk) * NSUB + d0 + dd];
    }
    __syncthreads();
    int dd = t >> 3, seg = t & 7;
    uint4 v = *(const uint4*)&sT[dd][seg * 16];
    *(uint4*)&idx8T[(size_t)(d0 + dd) * IN_DIM + k0 + seg * 16] = v;
}

// ---- main: barrier-free, wave-independent PQ-GEMM -------------------------
//
// KSPLIT=16 -> 2816 fine-grained blocks (10.7/CU queue). XCD decode keeps all
// 16 k-siblings of an nblk on one XCD (codebook slice L2-resident there).
// Reads f32 vecs/x directly, converts to bf16 in-register (no pack kernel).
// Chunk loop is software-pipelined: gathers for chunk c+1 issue between the
// transpose-writes and B-reads of chunk c (per-wave DS in-order; sV4/sW are
// wave-local), hiding gather latency under MFMA.
__global__ __launch_bounds__(256, 4) void pq_main(
    const float* __restrict__ xf, const float4* __restrict__ vf4,
    const uchar_t* __restrict__ idx8T, float* __restrict__ slab)
{
    __shared__ uint4  sV4[4 * 512];        // 32 KB: per-wave 2x256 codewords (bf16)
    __shared__ uint_t sW32[4 * 16 * 32];   //  8 KB: per-wave 16 rows x 64 k (swizzled)

    const int id  = blockIdx.x;
    const int xcd = id & 7;
    const int s   = id >> 3;               // 0..351
    const int nblk = xcd * NPX + (s % NPX);
    const int kblk = s / NPX;              // 0..15
    if (nblk >= NBLK) return;

    const int t    = threadIdx.x;
    const int w    = t >> 6;
    const int lane = t & 63;
    const int d0   = nblk * DTILE;
    const int kbase = kblk * KPB;

    const int l15 = lane & 15;
    const int l4  = lane >> 4;
    const int dl  = lane >> 5;             // 0..1 : subspace within wave
    const int q   = lane & 31;             // 0..31 : k-pair within chunk

    // --- stage codebook slice from f32, convert to bf16 in-register
    // wave w owns rows d0+2w, d0+2w+1: 2 x 256 codewords x 32 B f32
    {
        const float4* src4 = vf4 + (size_t)(d0 + w * 2) * (KSQ * DSUB / 4);
        #pragma unroll
        for (int p = 0; p < 8; ++p) {
            float4 v0 = src4[(p * 64 + lane) * 2];
            float4 v1 = src4[(p * 64 + lane) * 2 + 1];
            uint4 o;
            o.x = pack2(v0.x, v0.y); o.y = pack2(v0.z, v0.w);
            o.z = pack2(v1.x, v1.y); o.w = pack2(v1.z, v1.w);
            sV4[w * 512 + p * 64 + lane] = o;   // entry = codeword idx in wave's 2 rows
        }
    }

    // --- A fragments from f32 x, converted to bf16 (16 frags = 64 VGPR held)
    bf16x8 A[2][8];
    #pragma unroll
    for (int mt = 0; mt < 2; ++mt)
        #pragma unroll
        for (int kk = 0; kk < 8; ++kk) {
            const float* ap = &xf[(size_t)(mt * 16 + l15) * IN_DIM + kbase + kk * 32 + l4 * 8];
            float4 a0 = *(const float4*)ap;
            float4 a1 = *(const float4*)(ap + 4);
            union { bf16x8 v; uint4 u; } cv;
            cv.u.x = pack2(a0.x, a0.y); cv.u.y = pack2(a0.z, a0.w);
            cv.u.z = pack2(a1.x, a1.y); cv.u.w = pack2(a1.z, a1.w);
            A[mt][kk] = cv.v;
        }

    // --- idx bytes (4 x ushort: 2 codes per chunk for this lane)
    const uchar_t* idxrow = idx8T + (size_t)(d0 + w * 2 + dl) * IN_DIM + kbase;
    uint_t bb[NCHUNK];
    #pragma unroll
    for (int c = 0; c < NCHUNK; ++c)
        bb[c] = *(const ushort_t*)&idxrow[c * KC + q * 2];

    __builtin_amdgcn_sched_barrier(0);     // pin all preloads above the loop

    f32x4 acc[2];
    acc[0] = (f32x4)0.0f; acc[1] = (f32x4)0.0f;

    const int vbase = w * 512 + dl * 256;
    const int Rbase = (w * 16 + dl * 8) * 32;   // dword base of this lane's 8 rows

    // prime gathers for chunk 0 (in-order DS: stage writes complete first)
    uint4 g0 = sV4[vbase + (bb[0] & 255)];
    uint4 g1 = sV4[vbase + (bb[0] >> 8)];

    #pragma unroll
    for (int c = 0; c < NCHUNK; ++c) {
        // transpose 2x8 -> 8 b32 writes; xor-swizzle 16B units with row (=j)
        #pragma unroll
        for (int j = 0; j < 8; ++j) {
            const uint_t sel = (j & 1) ? 0x07060302u : 0x05040100u;
            uint_t a0 = (j >> 1) == 0 ? g0.x : (j >> 1) == 1 ? g0.y : (j >> 1) == 2 ? g0.z : g0.w;
            uint_t a1 = (j >> 1) == 0 ? g1.x : (j >> 1) == 1 ? g1.y : (j >> 1) == 2 ? g1.z : g1.w;
            uint_t wv = __builtin_amdgcn_perm(a1, a0, sel);   // [k even | k odd<<16]
            int dw = ((((q >> 2) ^ j) << 2) | (q & 3));
            sW32[Rbase + j * 32 + dw] = wv;
        }

        // issue next chunk's gathers NOW: latency overlaps B-reads + MFMA
        uint4 n0 = g0, n1 = g1;
        if (c + 1 < NCHUNK) {
            n0 = sV4[vbase + (bb[c + 1] & 255)];
            n1 = sV4[vbase + (bb[c + 1] >> 8)];
        }

        // B read (swizzled) + MFMA
        #pragma unroll
        for (int kq = 0; kq < 2; ++kq) {
            int u16 = (kq * 4 + l4) ^ (l15 & 7);
            bf16x8 B = *(const bf16x8*)
                ((const char*)sW32 + (w * 16 + l15) * 128 + u16 * 16);
            #pragma unroll
            for (int mt = 0; mt < 2; ++mt)
                acc[mt] = __builtin_amdgcn_mfma_f32_16x16x32_bf16(
                    A[mt][c * 2 + kq], B, acc[mt], 0, 0, 0);
        }
        g0 = n0; g1 = n1;
    }

    // --- dense store to this kblk's slab (no atomics)
    float* sl = slab + (size_t)kblk * BATCH * OUT_DIM;
    const int col = nblk * NTILE + w * 16 + l15;
    #pragma unroll
    for (int mt = 0; mt < 2; ++mt)
        #pragma unroll
        for (int r = 0; r < 4; ++r)
            sl[(size_t)(mt * 16 + l4 * 4 + r) * OUT_DIM + col] = acc[mt][r];
}

// ---- reduce: out = bias + sum_k slabs -------------------------------------
__global__ __launch_bounds__(256) void pq_reduce(
    const float* __restrict__ slab, const float* __restrict__ bias,
    float* __restrict__ out)
{
    int i = blockIdx.x * 256 + threadIdx.x;        // < 88064
    int m = i / (OUT_DIM / 4), n4 = i - m * (OUT_DIM / 4);
    float4 s = ((const float4*)bias)[n4];
    #pragma unroll
    for (int kb = 0; kb < KSPLIT; ++kb) {
        float4 v = ((const float4*)slab)[(size_t)(kb * BATCH + m) * (OUT_DIM / 4) + n4];
        s.x += v.x; s.y += v.y; s.z += v.z; s.w += v.w;
    }
    ((float4*)out)[(size_t)m * (OUT_DIM / 4) + n4] = s;
}

extern "C" void kernel_launch(void* const* d_in, const int* in_sizes, int n_in,
                              void* d_out, int out_size, void* d_ws, size_t ws_size,
                              hipStream_t stream) {
    const float* x    = (const float*)d_in[0];
    const float* vecs = (const float*)d_in[1];
    const float* bias = (const float*)d_in[2];
    const int*   idx  = (const int*)d_in[3];
    float* out = (float*)d_out;

    uchar_t* idx8T = (uchar_t*)((char*)d_ws + IDXT_OFF);
    float*   slab  = (float*)((char*)d_ws + SLAB_OFF);

    pq_prep<<<IDXT_BLK, 256, 0, stream>>>(idx, idx8T);
    pq_main<<<GRID_MAIN, 256, 0, stream>>>(
        x, (const float4*)vecs, idx8T, slab);
    pq_reduce<<<(BATCH * OUT_DIM / 4) / 256, 256, 0, stream>>>(slab, bias, out);
}

// Round 9
// 114.288 us; speedup vs baseline: 1.1719x; 1.1719x over previous
//
#include <hip/hip_runtime.h>

#define IN_DIM  4096
#define OUT_DIM 11008
#define NSUB    1376
#define KSQ     256
#define DSUB    8
#define BATCH   32

#define DTILE   8                    // subspaces per block
#define NTILE   64                   // output cols per block
#define KC      64                   // k per chunk
#define KSPLIT  16                   // k-blocks per output column
#define KPB     (IN_DIM / KSPLIT)    // 256
#define NCHUNK  (KPB / KC)           // 4
#define NBLK    (OUT_DIM / NTILE)    // 172
#define NBLKP   176                  // padded: 8 XCDs * 22
#define NPX     (NBLKP / 8)          // 22 nblk per XCD
#define GRID_MAIN (NBLKP * KSPLIT)   // 2816

typedef unsigned short ushort_t;
typedef unsigned int   uint_t;
typedef unsigned char  uchar_t;
typedef __attribute__((ext_vector_type(8))) short bf16x8;
typedef __attribute__((ext_vector_type(4))) float f32x4;

// workspace layout (bytes)
#define VEC_N    (NSUB * KSQ * DSUB)              // 2818048 floats
#define XBF_OFF  (VEC_N * 2)                      // 5636096  : xbf (bf16 x)
#define IDXT_OFF (XBF_OFF + BATCH * IN_DIM * 2)   // 5898240  : idx8T [NSUB][IN_DIM] u8
#define SLAB_OFF (IDXT_OFF + NSUB * IN_DIM)       // 11534336 : f32 slabs [KSPLIT][BATCH][OUT_DIM]
#define PREP_V   (VEC_N / 2)                      // 1409024 uints (2 bf16 each)
#define PREP_X   (BATCH * IN_DIM / 2)             // 65536
#define PREP_N   (PREP_V + PREP_X)                // 1474560 = 5760 * 256
#define PACK_BLK (PREP_N / 256)                   // 5760
#define IDXT_BLK ((IN_DIM / 128) * (NSUB / 32))   // 1376

__device__ __forceinline__ ushort_t f2bf(float f) {
    union { float f; uint_t u; } a; a.f = f;
    uint_t u = a.u;
    u += 0x7fffu + ((u >> 16) & 1u);   // round-to-nearest-even
    return (ushort_t)(u >> 16);
}

// opaque register fence on SCALAR components (128-bit tied operands are
// unsupported: "tied indirect register inputs" — round-8 compile failure)
__device__ __forceinline__ void pin4(uint4& x) {
    asm volatile("" : "+v"(x.x), "+v"(x.y), "+v"(x.z), "+v"(x.w));
}
__device__ __forceinline__ void pin1(uint_t& x) { asm volatile("" : "+v"(x)); }
__device__ __forceinline__ bf16x8 as_bf16x8(uint4 u) {
    union { uint4 u; bf16x8 v; } c; c.u = u; return c.v;
}

// ---- prep: bf16-pack codebook + x, AND transpose idx -> u8 [d][k] ---------
__global__ __launch_bounds__(256) void pq_prep(
    const float* __restrict__ x, const float* __restrict__ vecs,
    const int* __restrict__ idx,
    uint_t* __restrict__ vbf, uint_t* __restrict__ xbf,
    uchar_t* __restrict__ idx8T)
{
    __shared__ uchar_t sT[32][144];
    const int t = threadIdx.x;

    if (blockIdx.x < PACK_BLK) {
        int tid = blockIdx.x * 256 + t;
        if (tid < PREP_V) {
            float2 v = ((const float2*)vecs)[tid];
            vbf[tid] = (uint_t)f2bf(v.x) | ((uint_t)f2bf(v.y) << 16);
        } else {
            int i = tid - PREP_V;
            float2 v = ((const float2*)x)[i];
            xbf[i] = (uint_t)f2bf(v.x) | ((uint_t)f2bf(v.y) << 16);
        }
        return;
    }

    // idx transpose path
    const int bid = blockIdx.x - PACK_BLK;
    const int k0 = (bid & 31) * 128, d0 = (bid >> 5) * 32;
    #pragma unroll
    for (int p = 0; p < 16; ++p) {
        int f = p * 256 + t;           // 0..4095
        int kk = f >> 5, dd = f & 31;
        sT[dd][kk] = (uchar_t)idx[(size_t)(k0 + kk) * NSUB + d0 + dd];
    }
    __syncthreads();
    int dd = t >> 3, seg = t & 7;
    uint4 v = *(const uint4*)&sT[dd][seg * 16];
    *(uint4*)&idx8T[(size_t)(d0 + dd) * IN_DIM + k0 + seg * 16] = v;
}

// ---- main: barrier-free, wave-independent PQ-GEMM -------------------------
//
// All global loads (8 codebook-stage b128, 16 A b128, 4 idx ushort) issue
// back-to-back up front; A and idx results are PINNED in registers with an
// opaque asm fence so the compiler cannot re-load them inside the loop
// (VGPR_Count ~52 in prior rounds proved it was doing exactly that). The
// chunk loop is then pure LDS + VALU + MFMA with c+1 gathers pipelined.
// XCD decode keeps all 16 k-siblings of an nblk on one XCD's L2.
__global__ __launch_bounds__(256, 4) void pq_main(
    const ushort_t* __restrict__ xbfu, const uint4* __restrict__ vbf4,
    const uchar_t* __restrict__ idx8T, float* __restrict__ slab)
{
    __shared__ uint4  sV4[4 * 512];        // 32 KB: per-wave 2x256 codewords
    __shared__ uint_t sW32[4 * 16 * 32];   //  8 KB: per-wave 16 rows x 64 k (swizzled)

    const int id  = blockIdx.x;
    const int xcd = id & 7;
    const int s   = id >> 3;               // 0..351
    const int nblk = xcd * NPX + (s % NPX);
    const int kblk = s / NPX;              // 0..15
    if (nblk >= NBLK) return;

    const int t    = threadIdx.x;
    const int w    = t >> 6;
    const int lane = t & 63;
    const int d0   = nblk * DTILE;
    const int kbase = kblk * KPB;

    const int l15 = lane & 15;
    const int l4  = lane >> 4;
    const int dl  = lane >> 5;             // 0..1 : subspace within wave
    const int q   = lane & 31;             // 0..31 : k-pair within chunk

    // --- issue codebook stage loads (8 x b128, coalesced)
    uint4 vst[8];
    {
        const size_t src0 = (size_t)(d0 + w * 2) * KSQ;   // uint4 units
        #pragma unroll
        for (int p = 0; p < 8; ++p)
            vst[p] = vbf4[src0 + p * 64 + lane];
    }

    // --- issue ALL A-fragment loads (16 x b128)
    uint4 A[2][8];
    #pragma unroll
    for (int mt = 0; mt < 2; ++mt)
        #pragma unroll
        for (int kk = 0; kk < 8; ++kk)
            A[mt][kk] = *(const uint4*)
                &xbfu[(size_t)(mt * 16 + l15) * IN_DIM + kbase + kk * 32 + l4 * 8];

    // --- issue idx byte loads (4 x ushort)
    const uchar_t* idxrow = idx8T + (size_t)(d0 + w * 2 + dl) * IN_DIM + kbase;
    uint_t bb[NCHUNK];
    #pragma unroll
    for (int c = 0; c < NCHUNK; ++c)
        bb[c] = *(const ushort_t*)&idxrow[c * KC + q * 2];

    // --- commit codebook to LDS (waits only the 8 stage loads; A/idx in flight)
    #pragma unroll
    for (int p = 0; p < 8; ++p)
        sV4[w * 512 + p * 64 + lane] = vst[p];

    // --- pin A and idx in registers (opaque to the optimizer)
    #pragma unroll
    for (int mt = 0; mt < 2; ++mt)
        #pragma unroll
        for (int kk = 0; kk < 8; ++kk)
            pin4(A[mt][kk]);
    #pragma unroll
    for (int c = 0; c < NCHUNK; ++c)
        pin1(bb[c]);

    __builtin_amdgcn_sched_barrier(0);     // nothing sinks into the loop

    f32x4 acc[2];
    acc[0] = (f32x4)0.0f; acc[1] = (f32x4)0.0f;

    const int vbase = w * 512 + dl * 256;
    const int Rbase = (w * 16 + dl * 8) * 32;   // dword base of this lane's 8 rows

    // prime gathers for chunk 0 (per-wave DS in-order: stage writes land first)
    uint4 g0 = sV4[vbase + (bb[0] & 255)];
    uint4 g1 = sV4[vbase + (bb[0] >> 8)];

    #pragma unroll
    for (int c = 0; c < NCHUNK; ++c) {
        // transpose 2x8 -> 8 b32 writes; xor-swizzle 16B units with row (=j)
        #pragma unroll
        for (int j = 0; j < 8; ++j) {
            const uint_t sel = (j & 1) ? 0x07060302u : 0x05040100u;
            uint_t a0 = (j >> 1) == 0 ? g0.x : (j >> 1) == 1 ? g0.y : (j >> 1) == 2 ? g0.z : g0.w;
            uint_t a1 = (j >> 1) == 0 ? g1.x : (j >> 1) == 1 ? g1.y : (j >> 1) == 2 ? g1.z : g1.w;
            uint_t wv = __builtin_amdgcn_perm(a1, a0, sel);   // [k even | k odd<<16]
            int dw = ((((q >> 2) ^ j) << 2) | (q & 3));
            sW32[Rbase + j * 32 + dw] = wv;
        }

        // issue next chunk's gathers NOW: latency overlaps B-reads + MFMA
        uint4 n0 = g0, n1 = g1;
        if (c + 1 < NCHUNK) {
            n0 = sV4[vbase + (bb[c + 1] & 255)];
            n1 = sV4[vbase + (bb[c + 1] >> 8)];
        }

        // B read (swizzled) + MFMA
        #pragma unroll
        for (int kq = 0; kq < 2; ++kq) {
            int u16 = (kq * 4 + l4) ^ (l15 & 7);
            bf16x8 B = *(const bf16x8*)
                ((const char*)sW32 + (w * 16 + l15) * 128 + u16 * 16);
            #pragma unroll
            for (int mt = 0; mt < 2; ++mt)
                acc[mt] = __builtin_amdgcn_mfma_f32_16x16x32_bf16(
                    as_bf16x8(A[mt][c * 2 + kq]), B, acc[mt], 0, 0, 0);
        }
        g0 = n0; g1 = n1;
    }

    // --- dense store to this kblk's slab (no atomics)
    float* sl = slab + (size_t)kblk * BATCH * OUT_DIM;
    const int col = nblk * NTILE + w * 16 + l15;
    #pragma unroll
    for (int mt = 0; mt < 2; ++mt)
        #pragma unroll
        for (int r = 0; r < 4; ++r)
            sl[(size_t)(mt * 16 + l4 * 4 + r) * OUT_DIM + col] = acc[mt][r];
}

// ---- reduce: out = bias + sum_k slabs -------------------------------------
__global__ __launch_bounds__(256) void pq_reduce(
    const float* __restrict__ slab, const float* __restrict__ bias,
    float* __restrict__ out)
{
    int i = blockIdx.x * 256 + threadIdx.x;        // < 88064
    int m = i / (OUT_DIM / 4), n4 = i - m * (OUT_DIM / 4);
    float4 s = ((const float4*)bias)[n4];
    #pragma unroll
    for (int kb = 0; kb < KSPLIT; ++kb) {
        float4 v = ((const float4*)slab)[(size_t)(kb * BATCH + m) * (OUT_DIM / 4) + n4];
        s.x += v.x; s.y += v.y; s.z += v.z; s.w += v.w;
    }
    ((float4*)out)[(size_t)m * (OUT_DIM / 4) + n4] = s;
}

extern "C" void kernel_launch(void* const* d_in, const int* in_sizes, int n_in,
                              void* d_out, int out_size, void* d_ws, size_t ws_size,
                              hipStream_t stream) {
    const float* x    = (const float*)d_in[0];
    const float* vecs = (const float*)d_in[1];
    const float* bias = (const float*)d_in[2];
    const int*   idx  = (const int*)d_in[3];
    float* out = (float*)d_out;

    uint_t*  vbf   = (uint_t*)d_ws;
    uint_t*  xbf   = (uint_t*)((char*)d_ws + XBF_OFF);
    uchar_t* idx8T = (uchar_t*)((char*)d_ws + IDXT_OFF);
    float*   slab  = (float*)((char*)d_ws + SLAB_OFF);

    pq_prep<<<PACK_BLK + IDXT_BLK, 256, 0, stream>>>(x, vecs, idx, vbf, xbf, idx8T);
    pq_main<<<GRID_MAIN, 256, 0, stream>>>(
        (const ushort_t*)xbf, (const uint4*)vbf, idx8T, slab);
    pq_reduce<<<(BATCH * OUT_DIM / 4) / 256, 256, 0, stream>>>(slab, bias, out);
}